// Round 14
// baseline (153.062 us; speedup 1.0000x reference)
//
#include <hip/hip_runtime.h>

#define TWO_PI_F 6.283185307179586f
#define EPS_F 1e-6f
#define LOG2E_F 1.4426950408889634f
#define BATCH 32

#if __has_builtin(__builtin_amdgcn_exp2f)
#define EXP2F(x) __builtin_amdgcn_exp2f(x)
#else
#define EXP2F(x) exp2f(x)
#endif

typedef float v2f __attribute__((ext_vector_type(2)));

// Replace non-finite by 0 (bit test so fast-math can't fold it away).
__device__ __forceinline__ float sane(float x) {
    return ((__float_as_uint(x) & 0x7f800000u) == 0x7f800000u) ? 0.f : x;
}

// ---------------------------------------------------------------------------
// Fused layer (round-13 proven): [prev batchnorm] -> gm_convolve ->
// eval_at_centers (poly form, packed v_pk_fma, 2-deep pipelined LDS
// broadcast, bare v_exp) -> relu_fit (stable-rank top-KOUT) -> outputs.
// Used for layers 1 and 3.
// ---------------------------------------------------------------------------
template<int LO, int LI, int ND, int NK, int NCOMP, int KOUT,
         int KP, int TPG, int G, bool FIRST>
__global__ __launch_bounds__(TPG*G) void layer_kernel(
    const float* __restrict__ in_x,
    const float* __restrict__ prev_sel,
    const float* __restrict__ prev_tot,
    const float* __restrict__ kern,
    const float* __restrict__ bias,
    float* __restrict__ out_sel,
    float* __restrict__ out_tot)
{
    constexpr int KUSE   = NCOMP / KP;
    static_assert(KUSE * KP == NCOMP, "exact k tiling required");
    constexpr int CHUNK  = (NCOMP + G - 1) / G;
    constexpr int NCOMP4 = (NCOMP + 3) & ~3;
    constexpr int NQn    = NCOMP4 / 4;
    constexpr int CQ     = (NQn + G - 1) / G;
    constexpr int NPAIR  = KP / 2;
    constexpr int PPAD   = NPAIR > 0 ? NPAIR : 1;
    constexpr bool ODD   = (KP & 1) != 0;

    const int b   = blockIdx.x / LO;
    const int lo  = blockIdx.x % LO;
    const int tid = threadIdx.x;
    const int g   = tid / TPG;
    const int kt  = tid % TPG;
    const bool active = (kt < KUSE);

    struct StageT {
        float4 d_c[LI*ND];
        float4 k_c[LI*NK];
        float  d_w[LI*ND], d_px[LI*ND], d_py[LI*ND];
        float  k_w[LI*NK], k_px[LI*NK], k_py[LI*NK];
    };
    constexpr size_t ACCB = (size_t)(G > 1 ? (G-1)*TPG*KP : 1) * sizeof(float);
    constexpr size_t UB   = sizeof(StageT) > ACCB ? sizeof(StageT) : ACCB;
    __shared__ __align__(16) unsigned char u_smem[UB];
    StageT& st    = *reinterpret_cast<StageT*>(u_smem);
    float* accbuf = reinterpret_cast<float*>(u_smem);

    __shared__ float2 cPos[NCOMP];
    __shared__ float4 nP[NCOMP];
    __shared__ float4 nQ[NCOMP];
    __shared__ float4 cC[NCOMP];
    __shared__ float  w2s[NCOMP];
    __shared__ __align__(16) float a2s[NCOMP4];
    __shared__ float  scr[64];
    __shared__ float  selint[32];
    __shared__ float  dscale[LI];

    if constexpr (FIRST) {
        if (tid < ND) {
            const float* s = in_x + (size_t)(b*ND + tid)*7;
            const float w  = sane(s[0]);
            const float c0 = sane(s[3]), c1 = sane(s[4]), c2 = sane(s[5]), c3 = sane(s[6]);
            st.d_w[tid] = w; st.d_px[tid] = sane(s[1]); st.d_py[tid] = sane(s[2]);
            st.d_c[tid] = make_float4(c0, c1, c2, c3);
            const float det = c0*c3 - c1*c2;
            scr[tid] = sane(fabsf(w) * TWO_PI_F * sqrtf(fmaxf(det, EPS_F)));
        }
        __syncthreads();
        if (tid == 0) {
            float s = 0.f;
            for (int i = 0; i < ND; ++i) s += scr[i];
            dscale[0] = 1.f / (s + EPS_F);
        }
        __syncthreads();
        if (tid < ND) st.d_w[tid] = sane(st.d_w[tid] * dscale[0]);
    } else {
        if (tid < LI) {
            float s = 0.f;
            for (int bb = 0; bb < BATCH; ++bb) s += prev_tot[bb*LI + tid];
            dscale[tid] = 1.f / (s / (float)BATCH + EPS_F);
        }
        __syncthreads();
        if (tid < LI*ND) {
            const int li = tid / ND;
            const float* s = prev_sel + (size_t)(b*LI*ND + tid)*7;
            st.d_w[tid]  = sane(s[0] * dscale[li]);
            st.d_px[tid] = s[1]; st.d_py[tid] = s[2];
            st.d_c[tid]  = make_float4(s[3], s[4], s[5], s[6]);
        }
    }
    if (tid < LI*NK) {
        const float* s = kern + (size_t)(lo*LI*NK + tid)*7;
        st.k_w[tid]  = sane(s[0]);
        st.k_px[tid] = sane(s[1]); st.k_py[tid] = sane(s[2]);
        st.k_c[tid]  = make_float4(sane(s[3]), sane(s[4]), sane(s[5]), sane(s[6]));
    }
    __syncthreads();

    if (tid < NCOMP) {
        const int li = tid / (ND*NK);
        const int r  = tid % (ND*NK);
        const int nd = r / NK, nk = r % NK;
        const int di = li*ND + nd, ki = li*NK + nk;
        const float4 dc = st.d_c[di], kc = st.k_c[ki];
        const float c0 = dc.x + kc.x, c1 = dc.y + kc.y, c2 = dc.z + kc.z, c3 = dc.w + kc.w;
        const float dd = dc.x*dc.w - dc.y*dc.z;
        const float dk = kc.x*kc.w - kc.y*kc.z;
        const float ds = c0*c3 - c1*c2;
        const float w  = sane(st.d_w[di]*st.k_w[ki]*TWO_PI_F*sqrtf(fmaxf(dd*dk, 0.f) / fmaxf(ds, EPS_F)));
        const float px = sane(st.d_px[di] + st.k_px[ki]);
        const float py = sane(st.d_py[di] + st.k_py[ki]);
        const float inv = -0.5f * LOG2E_F / ds;
        const float a   = sane(c3*inv);
        const float bb  = sane(-(c1 + c2)*inv);
        const float cc  = sane(c0*inv);
        const float dd2 = sane(-(2.f*a*px + bb*py));
        const float ee  = sane(-(2.f*cc*py + bb*px));
        const float ff  = sane((a*px + bb*py)*px + cc*py*py);
        cPos[tid] = make_float2(px, py);
        nP[tid]   = make_float4(a, bb, cc, dd2);
        nQ[tid]   = make_float4(ee, ff, w, 0.f);
        cC[tid]   = make_float4(sane(c0), sane(c1), sane(c2), sane(c3));
    }
    __syncthreads();

    v2f kxP[PPAD], kyP[PPAD], kx2P[PPAD], ky2P[PPAD], kxyP[PPAD], accP[PPAD];
    float kxS = 0.f, kyS = 0.f, kx2S = 0.f, ky2S = 0.f, kxyS = 0.f, accS = 0.f;
    #pragma unroll
    for (int p = 0; p < NPAIR; ++p) {
        float x0 = 0.f, y0 = 0.f, x1 = 0.f, y1 = 0.f;
        if (active) {
            const float2 p0 = cPos[kt + (2*p    )*KUSE];
            const float2 p1 = cPos[kt + (2*p + 1)*KUSE];
            x0 = p0.x; y0 = p0.y; x1 = p1.x; y1 = p1.y;
        }
        v2f kx; kx.x = x0; kx.y = x1;
        v2f ky; ky.x = y0; ky.y = y1;
        kxP[p] = kx; kyP[p] = ky;
        kx2P[p] = kx*kx; ky2P[p] = ky*ky; kxyP[p] = kx*ky;
        v2f z; z.x = 0.f; z.y = 0.f; accP[p] = z;
    }
    if constexpr (ODD) {
        if (active) { const float2 pz = cPos[kt + (KP-1)*KUSE]; kxS = pz.x; kyS = pz.y; }
        kx2S = kxS*kxS; ky2S = kyS*kyS; kxyS = kxS*kyS;
    }
    {
        const int n0 = g*CHUNK;
        const int n1 = (n0 + CHUNK < NCOMP) ? (n0 + CHUNK) : NCOMP;
        if (n0 < n1) {
            float4 P = nP[n0], Q = nQ[n0];
            #pragma unroll 2
            for (int n = n0; n < n1; ++n) {
                const int nn = (n + 1 < n1) ? n + 1 : n0;
                const float4 Pn = nP[nn];
                const float4 Qn = nQ[nn];
                v2f Pa; Pa.x = P.x; Pa.y = P.x;
                v2f Pb; Pb.x = P.y; Pb.y = P.y;
                v2f Pc; Pc.x = P.z; Pc.y = P.z;
                v2f Pd; Pd.x = P.w; Pd.y = P.w;
                v2f Qe; Qe.x = Q.x; Qe.y = Q.x;
                v2f Qf; Qf.x = Q.y; Qf.y = Q.y;
                v2f Qw; Qw.x = Q.z; Qw.y = Q.z;
                #pragma unroll
                for (int p = 0; p < NPAIR; ++p) {
                    const v2f md = __builtin_elementwise_fma(Pa, kx2P[p],
                                   __builtin_elementwise_fma(Pb, kxyP[p],
                                   __builtin_elementwise_fma(Pc, ky2P[p],
                                   __builtin_elementwise_fma(Pd, kxP[p],
                                   __builtin_elementwise_fma(Qe, kyP[p], Qf)))));
                    v2f ex; ex.x = EXP2F(md.x); ex.y = EXP2F(md.y);
                    accP[p] = __builtin_elementwise_fma(Qw, ex, accP[p]);
                }
                if constexpr (ODD) {
                    const float md = fmaf(P.x, kx2S,
                                     fmaf(P.y, kxyS,
                                     fmaf(P.z, ky2S,
                                     fmaf(P.w, kxS,
                                     fmaf(Q.x, kyS, Q.y)))));
                    accS = fmaf(Q.z, EXP2F(md), accS);
                }
                P = Pn; Q = Qn;
            }
        }
    }
    float acc[KP];
    #pragma unroll
    for (int p = 0; p < NPAIR; ++p) { acc[2*p] = accP[p].x; acc[2*p+1] = accP[p].y; }
    if constexpr (ODD) acc[KP-1] = accS;

    if (g > 0 && active) {
        #pragma unroll
        for (int j = 0; j < KP; ++j) accbuf[((g-1)*TPG + kt)*KP + j] = acc[j];
    }
    __syncthreads();

    const float bi = bias[lo];
    if (g == 0 && active) {
        #pragma unroll
        for (int j = 0; j < KP; ++j) {
            float s = acc[j];
            for (int gg = 1; gg < G; ++gg) s += accbuf[((gg-1)*TPG + kt)*KP + j];
            const float v  = s + bi;
            const float sc = fmaxf(v, 0.f) / (fabsf(v) + EPS_F);
            const int   k  = kt + j*KUSE;
            const float ww = sane(nQ[k].z * sc);
            w2s[k] = ww;
            a2s[k] = fabsf(ww);
        }
    }
    if constexpr (NCOMP4 > NCOMP) {
        if (tid >= NCOMP && tid < NCOMP4) a2s[tid] = -1.f;
    }
    __syncthreads();

    int rank[KP];
    float myv[KP];
    #pragma unroll
    for (int j = 0; j < KP; ++j) rank[j] = 0;
    if (active) {
        #pragma unroll
        for (int j = 0; j < KP; ++j) myv[j] = a2s[kt + j*KUSE];
        const int q0 = g*CQ;
        const int q1 = (q0 + CQ < NQn) ? (q0 + CQ) : NQn;
        for (int q = q0; q < q1; ++q) {
            const float4 v4 = ((const float4*)a2s)[q];
            #pragma unroll
            for (int c = 0; c < 4; ++c) {
                const float vj = (c == 0) ? v4.x : (c == 1) ? v4.y : (c == 2) ? v4.z : v4.w;
                const int   jj = 4*q + c;
                #pragma unroll
                for (int j = 0; j < KP; ++j) {
                    const int myk = kt + j*KUSE;
                    rank[j] += (vj > myv[j] || (vj == myv[j] && jj < myk)) ? 1 : 0;
                }
            }
        }
        if (g > 0) {
            #pragma unroll
            for (int j = 0; j < KP; ++j) accbuf[((g-1)*TPG + kt)*KP + j] = (float)rank[j];
        }
    }
    __syncthreads();

    if (g == 0 && active) {
        #pragma unroll
        for (int j = 0; j < KP; ++j) {
            int r = rank[j];
            for (int gg = 1; gg < G; ++gg) r += (int)accbuf[((gg-1)*TPG + kt)*KP + j];
            if (r < KOUT) {
                const int k = kt + j*KUSE;
                const float2 p = cPos[k];
                const float4 c = cC[k];
                const float ww = w2s[k];
                float* dst = out_sel + (size_t)((b*LO + lo)*KOUT + r)*7;
                dst[0] = ww; dst[1] = p.x; dst[2] = p.y;
                dst[3] = c.x; dst[4] = c.y; dst[5] = c.z; dst[6] = c.w;
                const float det = c.x*c.w - c.y*c.z;
                selint[r] = sane(fabsf(ww) * TWO_PI_F * sqrtf(fmaxf(det, EPS_F)));
            }
        }
    }
    __syncthreads();
    if (tid == 0) {
        float s = 0.f;
        for (int i = 0; i < KOUT; ++i) s += selint[i];
        out_tot[b*LO + lo] = s;
    }
}

// ---------------------------------------------------------------------------
// Layer-2 stage A: batchnorm + conv + PARTIAL eval over 1/NSPLIT of n.
// 384 blocks -> all 256 CUs busy (128 get 2 blocks = 8 waves/SIMD).
// ---------------------------------------------------------------------------
template<int LO, int LI, int ND, int NK, int NCOMP, int KP, int TPG, int G,
         int NSPLIT, int PADK>
__global__ __launch_bounds__(TPG*G) void eval_partial_kernel(
    const float* __restrict__ prev_sel,
    const float* __restrict__ prev_tot,
    const float* __restrict__ kern,
    float* __restrict__ part)          // (NSPLIT*B*LO, PADK)
{
    constexpr int KUSE  = NCOMP / KP;
    constexpr int CH2   = (NCOMP + NSPLIT - 1) / NSPLIT;
    constexpr int CHG   = (CH2 + G - 1) / G;
    constexpr int NPAIR = KP / 2;
    constexpr int PPAD  = NPAIR > 0 ? NPAIR : 1;
    constexpr bool ODD  = (KP & 1) != 0;

    const int unit = blockIdx.x;               // (h*BATCH + b)*LO + lo
    const int h    = unit / (BATCH*LO);
    const int rem  = unit % (BATCH*LO);
    const int b    = rem / LO;
    const int lo   = rem % LO;
    const int tid  = threadIdx.x;
    const int g    = tid / TPG;
    const int kt   = tid % TPG;
    const bool active = (kt < KUSE);

    struct StageT {
        float4 d_c[LI*ND];
        float4 k_c[LI*NK];
        float  d_w[LI*ND], d_px[LI*ND], d_py[LI*ND];
        float  k_w[LI*NK], k_px[LI*NK], k_py[LI*NK];
    };
    constexpr size_t ACCB = (size_t)(G > 1 ? (G-1)*TPG*KP : 1) * sizeof(float);
    constexpr size_t UB   = sizeof(StageT) > ACCB ? sizeof(StageT) : ACCB;
    __shared__ __align__(16) unsigned char u_smem[UB];
    StageT& st    = *reinterpret_cast<StageT*>(u_smem);
    float* accbuf = reinterpret_cast<float*>(u_smem);

    __shared__ float2 cPos[NCOMP];
    __shared__ float4 nP[NCOMP];
    __shared__ float4 nQ[NCOMP];
    __shared__ float  dscale[LI];

    if (tid < LI) {
        float s = 0.f;
        for (int bb = 0; bb < BATCH; ++bb) s += prev_tot[bb*LI + tid];
        dscale[tid] = 1.f / (s / (float)BATCH + EPS_F);
    }
    __syncthreads();
    if (tid < LI*ND) {
        const int li = tid / ND;
        const float* s = prev_sel + (size_t)(b*LI*ND + tid)*7;
        st.d_w[tid]  = sane(s[0] * dscale[li]);
        st.d_px[tid] = s[1]; st.d_py[tid] = s[2];
        st.d_c[tid]  = make_float4(s[3], s[4], s[5], s[6]);
    }
    if (tid < LI*NK) {
        const float* s = kern + (size_t)(lo*LI*NK + tid)*7;
        st.k_w[tid]  = sane(s[0]);
        st.k_px[tid] = sane(s[1]); st.k_py[tid] = sane(s[2]);
        st.k_c[tid]  = make_float4(sane(s[3]), sane(s[4]), sane(s[5]), sane(s[6]));
    }
    __syncthreads();

    if (tid < NCOMP) {
        const int li = tid / (ND*NK);
        const int r  = tid % (ND*NK);
        const int nd = r / NK, nk = r % NK;
        const int di = li*ND + nd, ki = li*NK + nk;
        const float4 dc = st.d_c[di], kc = st.k_c[ki];
        const float c0 = dc.x + kc.x, c1 = dc.y + kc.y, c2 = dc.z + kc.z, c3 = dc.w + kc.w;
        const float dd = dc.x*dc.w - dc.y*dc.z;
        const float dk = kc.x*kc.w - kc.y*kc.z;
        const float ds = c0*c3 - c1*c2;
        const float w  = sane(st.d_w[di]*st.k_w[ki]*TWO_PI_F*sqrtf(fmaxf(dd*dk, 0.f) / fmaxf(ds, EPS_F)));
        const float px = sane(st.d_px[di] + st.k_px[ki]);
        const float py = sane(st.d_py[di] + st.k_py[ki]);
        const float inv = -0.5f * LOG2E_F / ds;
        const float a   = sane(c3*inv);
        const float bb  = sane(-(c1 + c2)*inv);
        const float cc  = sane(c0*inv);
        const float dd2 = sane(-(2.f*a*px + bb*py));
        const float ee  = sane(-(2.f*cc*py + bb*px));
        const float ff  = sane((a*px + bb*py)*px + cc*py*py);
        cPos[tid] = make_float2(px, py);
        nP[tid]   = make_float4(a, bb, cc, dd2);
        nQ[tid]   = make_float4(ee, ff, w, 0.f);
    }
    __syncthreads();

    v2f kxP[PPAD], kyP[PPAD], kx2P[PPAD], ky2P[PPAD], kxyP[PPAD], accP[PPAD];
    float kxS = 0.f, kyS = 0.f, kx2S = 0.f, ky2S = 0.f, kxyS = 0.f, accS = 0.f;
    #pragma unroll
    for (int p = 0; p < NPAIR; ++p) {
        float x0 = 0.f, y0 = 0.f, x1 = 0.f, y1 = 0.f;
        if (active) {
            const float2 p0 = cPos[kt + (2*p    )*KUSE];
            const float2 p1 = cPos[kt + (2*p + 1)*KUSE];
            x0 = p0.x; y0 = p0.y; x1 = p1.x; y1 = p1.y;
        }
        v2f kx; kx.x = x0; kx.y = x1;
        v2f ky; ky.x = y0; ky.y = y1;
        kxP[p] = kx; kyP[p] = ky;
        kx2P[p] = kx*kx; ky2P[p] = ky*ky; kxyP[p] = kx*ky;
        v2f z; z.x = 0.f; z.y = 0.f; accP[p] = z;
    }
    if constexpr (ODD) {
        if (active) { const float2 pz = cPos[kt + (KP-1)*KUSE]; kxS = pz.x; kyS = pz.y; }
        kx2S = kxS*kxS; ky2S = kyS*kyS; kxyS = kxS*kyS;
    }
    {
        const int nlo = h*CH2;
        const int nhi = (nlo + CH2 < NCOMP) ? (nlo + CH2) : NCOMP;
        const int n0  = nlo + g*CHG;
        const int n1  = (n0 + CHG < nhi) ? (n0 + CHG) : nhi;
        if (n0 < n1) {
            float4 P = nP[n0], Q = nQ[n0];
            #pragma unroll 2
            for (int n = n0; n < n1; ++n) {
                const int nn = (n + 1 < n1) ? n + 1 : n0;
                const float4 Pn = nP[nn];
                const float4 Qn = nQ[nn];
                v2f Pa; Pa.x = P.x; Pa.y = P.x;
                v2f Pb; Pb.x = P.y; Pb.y = P.y;
                v2f Pc; Pc.x = P.z; Pc.y = P.z;
                v2f Pd; Pd.x = P.w; Pd.y = P.w;
                v2f Qe; Qe.x = Q.x; Qe.y = Q.x;
                v2f Qf; Qf.x = Q.y; Qf.y = Q.y;
                v2f Qw; Qw.x = Q.z; Qw.y = Q.z;
                #pragma unroll
                for (int p = 0; p < NPAIR; ++p) {
                    const v2f md = __builtin_elementwise_fma(Pa, kx2P[p],
                                   __builtin_elementwise_fma(Pb, kxyP[p],
                                   __builtin_elementwise_fma(Pc, ky2P[p],
                                   __builtin_elementwise_fma(Pd, kxP[p],
                                   __builtin_elementwise_fma(Qe, kyP[p], Qf)))));
                    v2f ex; ex.x = EXP2F(md.x); ex.y = EXP2F(md.y);
                    accP[p] = __builtin_elementwise_fma(Qw, ex, accP[p]);
                }
                if constexpr (ODD) {
                    const float md = fmaf(P.x, kx2S,
                                     fmaf(P.y, kxyS,
                                     fmaf(P.z, ky2S,
                                     fmaf(P.w, kxS,
                                     fmaf(Q.x, kyS, Q.y)))));
                    accS = fmaf(Q.z, EXP2F(md), accS);
                }
                P = Pn; Q = Qn;
            }
        }
    }
    float acc[KP];
    #pragma unroll
    for (int p = 0; p < NPAIR; ++p) { acc[2*p] = accP[p].x; acc[2*p+1] = accP[p].y; }
    if constexpr (ODD) acc[KP-1] = accS;

    if (g > 0 && active) {
        #pragma unroll
        for (int j = 0; j < KP; ++j) accbuf[((g-1)*TPG + kt)*KP + j] = acc[j];
    }
    __syncthreads();
    if (g == 0 && active) {
        float* dst = part + (size_t)unit * PADK;
        #pragma unroll
        for (int j = 0; j < KP; ++j) {
            float s = acc[j];
            for (int gg = 1; gg < G; ++gg) s += accbuf[((gg-1)*TPG + kt)*KP + j];
            dst[kt + j*KUSE] = s;
        }
    }
}

// ---------------------------------------------------------------------------
// Layer-2 stage B: redo cheap conv (w/px/py/C), sum partials + bias, relu
// scale, stable rank, write selected comps + abs-integral. 192 x 640.
// ---------------------------------------------------------------------------
template<int LO, int LI, int ND, int NK, int NCOMP, int KOUT, int KP, int TPG,
         int G, int NSPLIT, int PADK>
__global__ __launch_bounds__(TPG*G) void merge_rank_kernel(
    const float* __restrict__ prev_sel,
    const float* __restrict__ prev_tot,
    const float* __restrict__ kern,
    const float* __restrict__ bias,
    const float* __restrict__ part,
    float* __restrict__ out_sel,
    float* __restrict__ out_tot)
{
    constexpr int KUSE   = NCOMP / KP;
    constexpr int NCOMP4 = (NCOMP + 3) & ~3;
    constexpr int NQn    = NCOMP4 / 4;
    constexpr int CQ     = (NQn + G - 1) / G;

    const int b   = blockIdx.x / LO;
    const int lo  = blockIdx.x % LO;
    const int tid = threadIdx.x;
    const int g   = tid / TPG;
    const int kt  = tid % TPG;
    const bool active = (kt < KUSE);

    struct StageT {
        float4 d_c[LI*ND];
        float4 k_c[LI*NK];
        float  d_w[LI*ND], d_px[LI*ND], d_py[LI*ND];
        float  k_w[LI*NK], k_px[LI*NK], k_py[LI*NK];
    };
    constexpr size_t ACCB = (size_t)(G > 1 ? (G-1)*TPG*KP : 1) * sizeof(float);
    constexpr size_t UB   = sizeof(StageT) > ACCB ? sizeof(StageT) : ACCB;
    __shared__ __align__(16) unsigned char u_smem[UB];
    StageT& st    = *reinterpret_cast<StageT*>(u_smem);
    float* accbuf = reinterpret_cast<float*>(u_smem);

    __shared__ float2 cPos[NCOMP];
    __shared__ float4 cC[NCOMP];
    __shared__ float  w2s[NCOMP];
    __shared__ __align__(16) float a2s[NCOMP4];
    __shared__ float  selint[32];
    __shared__ float  dscale[LI];

    if (tid < LI) {
        float s = 0.f;
        for (int bb = 0; bb < BATCH; ++bb) s += prev_tot[bb*LI + tid];
        dscale[tid] = 1.f / (s / (float)BATCH + EPS_F);
    }
    __syncthreads();
    if (tid < LI*ND) {
        const int li = tid / ND;
        const float* s = prev_sel + (size_t)(b*LI*ND + tid)*7;
        st.d_w[tid]  = sane(s[0] * dscale[li]);
        st.d_px[tid] = s[1]; st.d_py[tid] = s[2];
        st.d_c[tid]  = make_float4(s[3], s[4], s[5], s[6]);
    }
    if (tid < LI*NK) {
        const float* s = kern + (size_t)(lo*LI*NK + tid)*7;
        st.k_w[tid]  = sane(s[0]);
        st.k_px[tid] = sane(s[1]); st.k_py[tid] = sane(s[2]);
        st.k_c[tid]  = make_float4(sane(s[3]), sane(s[4]), sane(s[5]), sane(s[6]));
    }
    __syncthreads();

    const float bi = bias[lo];
    if (tid < NCOMP) {
        const int li = tid / (ND*NK);
        const int r  = tid % (ND*NK);
        const int nd = r / NK, nk = r % NK;
        const int di = li*ND + nd, ki = li*NK + nk;
        const float4 dc = st.d_c[di], kc = st.k_c[ki];
        const float c0 = dc.x + kc.x, c1 = dc.y + kc.y, c2 = dc.z + kc.z, c3 = dc.w + kc.w;
        const float dd = dc.x*dc.w - dc.y*dc.z;
        const float dk = kc.x*kc.w - kc.y*kc.z;
        const float ds = c0*c3 - c1*c2;
        const float w  = sane(st.d_w[di]*st.k_w[ki]*TWO_PI_F*sqrtf(fmaxf(dd*dk, 0.f) / fmaxf(ds, EPS_F)));
        cPos[tid] = make_float2(sane(st.d_px[di] + st.k_px[ki]),
                                sane(st.d_py[di] + st.k_py[ki]));
        cC[tid]   = make_float4(sane(c0), sane(c1), sane(c2), sane(c3));
        float v = bi;
        #pragma unroll
        for (int hh = 0; hh < NSPLIT; ++hh)
            v += part[(size_t)((hh*BATCH + b)*LO + lo) * PADK + tid];
        const float sc = fmaxf(v, 0.f) / (fabsf(v) + EPS_F);
        const float ww = sane(w * sc);
        w2s[tid] = ww;
        a2s[tid] = fabsf(ww);
    }
    if constexpr (NCOMP4 > NCOMP) {
        if (tid >= NCOMP && tid < NCOMP4) a2s[tid] = -1.f;
    }
    __syncthreads();

    int rank[KP];
    float myv[KP];
    #pragma unroll
    for (int j = 0; j < KP; ++j) rank[j] = 0;
    if (active) {
        #pragma unroll
        for (int j = 0; j < KP; ++j) myv[j] = a2s[kt + j*KUSE];
        const int q0 = g*CQ;
        const int q1 = (q0 + CQ < NQn) ? (q0 + CQ) : NQn;
        for (int q = q0; q < q1; ++q) {
            const float4 v4 = ((const float4*)a2s)[q];
            #pragma unroll
            for (int c = 0; c < 4; ++c) {
                const float vj = (c == 0) ? v4.x : (c == 1) ? v4.y : (c == 2) ? v4.z : v4.w;
                const int   jj = 4*q + c;
                #pragma unroll
                for (int j = 0; j < KP; ++j) {
                    const int myk = kt + j*KUSE;
                    rank[j] += (vj > myv[j] || (vj == myv[j] && jj < myk)) ? 1 : 0;
                }
            }
        }
        if (g > 0) {
            #pragma unroll
            for (int j = 0; j < KP; ++j) accbuf[((g-1)*TPG + kt)*KP + j] = (float)rank[j];
        }
    }
    __syncthreads();

    if (g == 0 && active) {
        #pragma unroll
        for (int j = 0; j < KP; ++j) {
            int r = rank[j];
            for (int gg = 1; gg < G; ++gg) r += (int)accbuf[((gg-1)*TPG + kt)*KP + j];
            if (r < KOUT) {
                const int k = kt + j*KUSE;
                const float2 p = cPos[k];
                const float4 c = cC[k];
                const float ww = w2s[k];
                float* dst = out_sel + (size_t)((b*LO + lo)*KOUT + r)*7;
                dst[0] = ww; dst[1] = p.x; dst[2] = p.y;
                dst[3] = c.x; dst[4] = c.y; dst[5] = c.z; dst[6] = c.w;
                const float det = c.x*c.w - c.y*c.z;
                selint[r] = sane(fabsf(ww) * TWO_PI_F * sqrtf(fmaxf(det, EPS_F)));
            }
        }
    }
    __syncthreads();
    if (tid == 0) {
        float s = 0.f;
        for (int i = 0; i < KOUT; ++i) s += selint[i];
        out_tot[b*LO + lo] = s;
    }
}

// Final: batchnorm3 scale (mean over batch) -> integrate -> log_softmax -> f32
__global__ __launch_bounds__(64) void final_kernel(
    const float* __restrict__ sel3,
    const float* __restrict__ tot3,
    float* __restrict__ out)
{
    const int b = blockIdx.x;
    const int tid = threadIdx.x;
    __shared__ float scale3[10], integ[10], red2[2];
    if (tid < 10) {
        float s = 0.f;
        for (int bb = 0; bb < BATCH; ++bb) s += tot3[bb*10 + tid];
        scale3[tid] = 1.f / (s / (float)BATCH + EPS_F);
    }
    __syncthreads();
    if (tid < 10) {
        float s = 0.f;
        const float* base = sel3 + (size_t)((b*10 + tid)*5)*7;
        for (int kk = 0; kk < 5; ++kk) {
            const float* c = base + kk*7;
            const float det = c[3]*c[6] - c[4]*c[5];
            s += c[0] * scale3[tid] * TWO_PI_F * sqrtf(fmaxf(det, EPS_F));
        }
        integ[tid] = sane(s);
    }
    __syncthreads();
    if (tid == 0) {
        float m = -1e30f;
        for (int l = 0; l < 10; ++l) m = fmaxf(m, integ[l]);
        float ss = 0.f;
        for (int l = 0; l < 10; ++l) ss += __expf(integ[l] - m);
        red2[0] = m; red2[1] = logf(ss);
    }
    __syncthreads();
    if (tid < 10) out[b*10 + tid] = integ[tid] - red2[0] - red2[1];
}

extern "C" void kernel_launch(void* const* d_in, const int* in_sizes, int n_in,
                              void* d_out, int out_size, void* d_ws, size_t ws_size,
                              hipStream_t stream)
{
    const float* in_x = (const float*)d_in[0];
    const float* k1   = (const float*)d_in[1];
    const float* k2   = (const float*)d_in[2];
    const float* k3   = (const float*)d_in[3];
    const float* b1   = (const float*)d_in[4];
    const float* b2   = (const float*)d_in[5];
    const float* b3   = (const float*)d_in[6];
    float* out = (float*)d_out;

    float* ws = (float*)d_ws;
    float* sel1 = ws;                  // 32*5*25*7  = 28000 floats
    float* tot1 = ws + 28000;          // 160
    float* sel2 = ws + 28160;          // 32*6*12*7  = 16128
    float* tot2 = ws + 44288;          // 192
    float* sel3 = ws + 44480;          // 32*10*5*7  = 11200
    float* tot3 = ws + 55680;          // 320
    float* part = ws + 56064;          // 2*192*640 = 245760 floats (~983 KB)

    // Layer 1: 320 comps, keep 25.  KP=5, TPG=64, G=16 -> 1024 threads.
    layer_kernel<5, 1, 64, 5, 320, 25, 5, 64, 16, true><<<BATCH*5, 1024, 0, stream>>>(
        in_x, nullptr, nullptr, k1, b1, sel1, tot1);
    // Layer 2a: partial eval, n split x2.  384 blocks x 1024 (KP=5,TPG=128,G=8).
    eval_partial_kernel<6, 5, 25, 5, 625, 5, 128, 8, 2, 640><<<BATCH*6*2, 1024, 0, stream>>>(
        sel1, tot1, k2, part);
    // Layer 2b: merge + rank + write.  192 blocks x 640 (KP=5,TPG=128,G=5).
    merge_rank_kernel<6, 5, 25, 5, 625, 12, 5, 128, 5, 2, 640><<<BATCH*6, 640, 0, stream>>>(
        sel1, tot1, k2, b2, part, sel2, tot2);
    // Layer 3: 360 comps, keep 5.  KP=6, TPG=64, G=12 -> 768 threads.
    layer_kernel<10, 6, 12, 5, 360, 5, 6, 64, 12, false><<<BATCH*10, 768, 0, stream>>>(
        nullptr, sel2, tot2, k3, b3, sel3, tot3);
    // Final: batchnorm + integrate + log_softmax.
    final_kernel<<<BATCH, 64, 0, stream>>>(sel3, tot3, out);
}

// Round 15
// 150.046 us; speedup vs baseline: 1.0201x; 1.0201x over previous
//
#include <hip/hip_runtime.h>

#define TWO_PI_F 6.283185307179586f
#define EPS_F 1e-6f
#define LOG2E_F 1.4426950408889634f
#define BATCH 32

#if __has_builtin(__builtin_amdgcn_exp2f)
#define EXP2F(x) __builtin_amdgcn_exp2f(x)
#else
#define EXP2F(x) exp2f(x)
#endif

typedef float v2f __attribute__((ext_vector_type(2)));

// Replace non-finite by 0 (bit test so fast-math can't fold it away).
__device__ __forceinline__ float sane(float x) {
    return ((__float_as_uint(x) & 0x7f800000u) == 0x7f800000u) ? 0.f : x;
}

// One fused layer (round-13 proven body): [prev batchnorm] -> gm_convolve ->
// eval_at_centers (poly form, packed v_pk_fma, 2-deep pipelined LDS broadcast,
// bare v_exp) -> relu_fit (stable-rank top-KOUT) -> outputs.
// FINAL=true additionally runs the net's tail (batchnorm3+integrate+
// log_softmax) in the LAST-completing block (device-scope release/acquire via
// threadfence+atomicAdd — a reduction tail needs no grid barrier).
template<int LO, int LI, int ND, int NK, int NCOMP, int KOUT,
         int KP, int TPG, int G, bool FIRST, bool FINAL>
__global__ __launch_bounds__(TPG*G) void layer_kernel(
    const float* __restrict__ in_x,            // FIRST: (B,1,64,7) f32
    const float* __restrict__ prev_sel,        // !FIRST: (B,LI,ND,7) f32
    const float* __restrict__ prev_tot,        // !FIRST: (B,LI) f32
    const float* __restrict__ kern,            // (LO,LI,NK,7) f32
    const float* __restrict__ bias,            // (LO,) f32
    float* __restrict__ out_sel,               // (B,LO,KOUT,7) f32
    float* __restrict__ out_tot,               // (B,LO) f32
    unsigned int* __restrict__ zero_cnt,       // L1: zero the L3 done-counter
    unsigned int* __restrict__ done,           // FINAL: completion counter
    float* __restrict__ fout)                  // FINAL: (B,10) f32 output
{
    constexpr int KUSE   = NCOMP / KP;
    static_assert(KUSE * KP == NCOMP, "exact k tiling required");
    constexpr int CHUNK  = (NCOMP + G - 1) / G;
    constexpr int NCOMP4 = (NCOMP + 3) & ~3;
    constexpr int NQn    = NCOMP4 / 4;
    constexpr int CQ     = (NQn + G - 1) / G;
    constexpr int NPAIR  = KP / 2;
    constexpr int PPAD   = NPAIR > 0 ? NPAIR : 1;
    constexpr bool ODD   = (KP & 1) != 0;

    const int b   = blockIdx.x / LO;
    const int lo  = blockIdx.x % LO;
    const int tid = threadIdx.x;
    const int g   = tid / TPG;
    const int kt  = tid % TPG;
    const bool active = (kt < KUSE);

    // L1 zeroes the L3 completion counter (stream order -> visible by L3).
    if (zero_cnt && blockIdx.x == 0 && tid == 0) *zero_cnt = 0u;

    struct StageT {
        float4 d_c[LI*ND];
        float4 k_c[LI*NK];
        float  d_w[LI*ND], d_px[LI*ND], d_py[LI*ND];
        float  k_w[LI*NK], k_px[LI*NK], k_py[LI*NK];
    };
    constexpr size_t ACCB = (size_t)(G > 1 ? (G-1)*TPG*KP : 1) * sizeof(float);
    constexpr size_t UB   = sizeof(StageT) > ACCB ? sizeof(StageT) : ACCB;
    __shared__ __align__(16) unsigned char u_smem[UB];
    StageT& st    = *reinterpret_cast<StageT*>(u_smem);
    float* accbuf = reinterpret_cast<float*>(u_smem);

    __shared__ float2 cPos[NCOMP];
    __shared__ float4 nP[NCOMP];    // a, b, c, d (log2e-folded quadform poly)
    __shared__ float4 nQ[NCOMP];    // e, f, w, 0
    __shared__ float4 cC[NCOMP];
    __shared__ float  w2s[NCOMP];
    __shared__ __align__(16) float a2s[NCOMP4];
    __shared__ float  scr[64];
    __shared__ float  selint[32];
    __shared__ float  dscale[LI];

    if constexpr (FIRST) {
        if (tid < ND) {
            const float* s = in_x + (size_t)(b*ND + tid)*7;
            const float w  = sane(s[0]);
            const float c0 = sane(s[3]), c1 = sane(s[4]), c2 = sane(s[5]), c3 = sane(s[6]);
            st.d_w[tid] = w; st.d_px[tid] = sane(s[1]); st.d_py[tid] = sane(s[2]);
            st.d_c[tid] = make_float4(c0, c1, c2, c3);
            const float det = c0*c3 - c1*c2;
            scr[tid] = sane(fabsf(w) * TWO_PI_F * sqrtf(fmaxf(det, EPS_F)));
        }
        __syncthreads();
        if (tid == 0) {
            float s = 0.f;
            for (int i = 0; i < ND; ++i) s += scr[i];
            dscale[0] = 1.f / (s + EPS_F);
        }
        __syncthreads();
        if (tid < ND) st.d_w[tid] = sane(st.d_w[tid] * dscale[0]);
    } else {
        if (tid < LI) {
            float s = 0.f;
            for (int bb = 0; bb < BATCH; ++bb) s += prev_tot[bb*LI + tid];
            dscale[tid] = 1.f / (s / (float)BATCH + EPS_F);
        }
        __syncthreads();
        if (tid < LI*ND) {
            const int li = tid / ND;
            const float* s = prev_sel + (size_t)(b*LI*ND + tid)*7;
            st.d_w[tid]  = sane(s[0] * dscale[li]);
            st.d_px[tid] = s[1]; st.d_py[tid] = s[2];
            st.d_c[tid]  = make_float4(s[3], s[4], s[5], s[6]);
        }
    }
    if (tid < LI*NK) {
        const float* s = kern + (size_t)(lo*LI*NK + tid)*7;
        st.k_w[tid]  = sane(s[0]);
        st.k_px[tid] = sane(s[1]); st.k_py[tid] = sane(s[2]);
        st.k_c[tid]  = make_float4(sane(s[3]), sane(s[4]), sane(s[5]), sane(s[6]));
    }
    __syncthreads();

    if (tid < NCOMP) {
        const int li = tid / (ND*NK);
        const int r  = tid % (ND*NK);
        const int nd = r / NK, nk = r % NK;
        const int di = li*ND + nd, ki = li*NK + nk;
        const float4 dc = st.d_c[di], kc = st.k_c[ki];
        const float c0 = dc.x + kc.x, c1 = dc.y + kc.y, c2 = dc.z + kc.z, c3 = dc.w + kc.w;
        const float dd = dc.x*dc.w - dc.y*dc.z;
        const float dk = kc.x*kc.w - kc.y*kc.z;
        const float ds = c0*c3 - c1*c2;
        const float w  = sane(st.d_w[di]*st.k_w[ki]*TWO_PI_F*sqrtf(fmaxf(dd*dk, 0.f) / fmaxf(ds, EPS_F)));
        const float px = sane(st.d_px[di] + st.k_px[ki]);
        const float py = sane(st.d_py[di] + st.k_py[ki]);
        const float inv = -0.5f * LOG2E_F / ds;
        const float a   = sane(c3*inv);
        const float bb  = sane(-(c1 + c2)*inv);
        const float cc  = sane(c0*inv);
        const float dd2 = sane(-(2.f*a*px + bb*py));
        const float ee  = sane(-(2.f*cc*py + bb*px));
        const float ff  = sane((a*px + bb*py)*px + cc*py*py);
        cPos[tid] = make_float2(px, py);
        nP[tid]   = make_float4(a, bb, cc, dd2);
        nQ[tid]   = make_float4(ee, ff, w, 0.f);
        cC[tid]   = make_float4(sane(c0), sane(c1), sane(c2), sane(c3));
    }
    __syncthreads();

    v2f kxP[PPAD], kyP[PPAD], kx2P[PPAD], ky2P[PPAD], kxyP[PPAD], accP[PPAD];
    float kxS = 0.f, kyS = 0.f, kx2S = 0.f, ky2S = 0.f, kxyS = 0.f, accS = 0.f;
    #pragma unroll
    for (int p = 0; p < NPAIR; ++p) {
        float x0 = 0.f, y0 = 0.f, x1 = 0.f, y1 = 0.f;
        if (active) {
            const float2 p0 = cPos[kt + (2*p    )*KUSE];
            const float2 p1 = cPos[kt + (2*p + 1)*KUSE];
            x0 = p0.x; y0 = p0.y; x1 = p1.x; y1 = p1.y;
        }
        v2f kx; kx.x = x0; kx.y = x1;
        v2f ky; ky.x = y0; ky.y = y1;
        kxP[p] = kx; kyP[p] = ky;
        kx2P[p] = kx*kx; ky2P[p] = ky*ky; kxyP[p] = kx*ky;
        v2f z; z.x = 0.f; z.y = 0.f; accP[p] = z;
    }
    if constexpr (ODD) {
        if (active) { const float2 pz = cPos[kt + (KP-1)*KUSE]; kxS = pz.x; kyS = pz.y; }
        kx2S = kxS*kxS; ky2S = kyS*kyS; kxyS = kxS*kyS;
    }
    {
        const int n0 = g*CHUNK;
        const int n1 = (n0 + CHUNK < NCOMP) ? (n0 + CHUNK) : NCOMP;
        if (n0 < n1) {
            float4 P = nP[n0], Q = nQ[n0];
            #pragma unroll 2
            for (int n = n0; n < n1; ++n) {
                const int nn = (n + 1 < n1) ? n + 1 : n0;
                const float4 Pn = nP[nn];
                const float4 Qn = nQ[nn];
                v2f Pa; Pa.x = P.x; Pa.y = P.x;
                v2f Pb; Pb.x = P.y; Pb.y = P.y;
                v2f Pc; Pc.x = P.z; Pc.y = P.z;
                v2f Pd; Pd.x = P.w; Pd.y = P.w;
                v2f Qe; Qe.x = Q.x; Qe.y = Q.x;
                v2f Qf; Qf.x = Q.y; Qf.y = Q.y;
                v2f Qw; Qw.x = Q.z; Qw.y = Q.z;
                #pragma unroll
                for (int p = 0; p < NPAIR; ++p) {
                    const v2f md = __builtin_elementwise_fma(Pa, kx2P[p],
                                   __builtin_elementwise_fma(Pb, kxyP[p],
                                   __builtin_elementwise_fma(Pc, ky2P[p],
                                   __builtin_elementwise_fma(Pd, kxP[p],
                                   __builtin_elementwise_fma(Qe, kyP[p], Qf)))));
                    v2f ex; ex.x = EXP2F(md.x); ex.y = EXP2F(md.y);
                    accP[p] = __builtin_elementwise_fma(Qw, ex, accP[p]);
                }
                if constexpr (ODD) {
                    const float md = fmaf(P.x, kx2S,
                                     fmaf(P.y, kxyS,
                                     fmaf(P.z, ky2S,
                                     fmaf(P.w, kxS,
                                     fmaf(Q.x, kyS, Q.y)))));
                    accS = fmaf(Q.z, EXP2F(md), accS);
                }
                P = Pn; Q = Qn;
            }
        }
    }
    float acc[KP];
    #pragma unroll
    for (int p = 0; p < NPAIR; ++p) { acc[2*p] = accP[p].x; acc[2*p+1] = accP[p].y; }
    if constexpr (ODD) acc[KP-1] = accS;

    if (g > 0 && active) {
        #pragma unroll
        for (int j = 0; j < KP; ++j) accbuf[((g-1)*TPG + kt)*KP + j] = acc[j];
    }
    __syncthreads();

    const float bi = bias[lo];
    if (g == 0 && active) {
        #pragma unroll
        for (int j = 0; j < KP; ++j) {
            float s = acc[j];
            for (int gg = 1; gg < G; ++gg) s += accbuf[((gg-1)*TPG + kt)*KP + j];
            const float v  = s + bi;
            const float sc = fmaxf(v, 0.f) / (fabsf(v) + EPS_F);
            const int   k  = kt + j*KUSE;
            const float ww = sane(nQ[k].z * sc);
            w2s[k] = ww;
            a2s[k] = fabsf(ww);
        }
    }
    if constexpr (NCOMP4 > NCOMP) {
        if (tid >= NCOMP && tid < NCOMP4) a2s[tid] = -1.f;
    }
    __syncthreads();

    int rank[KP];
    float myv[KP];
    #pragma unroll
    for (int j = 0; j < KP; ++j) rank[j] = 0;
    if (active) {
        #pragma unroll
        for (int j = 0; j < KP; ++j) myv[j] = a2s[kt + j*KUSE];
        const int q0 = g*CQ;
        const int q1 = (q0 + CQ < NQn) ? (q0 + CQ) : NQn;
        for (int q = q0; q < q1; ++q) {
            const float4 v4 = ((const float4*)a2s)[q];
            #pragma unroll
            for (int c = 0; c < 4; ++c) {
                const float vj = (c == 0) ? v4.x : (c == 1) ? v4.y : (c == 2) ? v4.z : v4.w;
                const int   jj = 4*q + c;
                #pragma unroll
                for (int j = 0; j < KP; ++j) {
                    const int myk = kt + j*KUSE;
                    rank[j] += (vj > myv[j] || (vj == myv[j] && jj < myk)) ? 1 : 0;
                }
            }
        }
        if (g > 0) {
            #pragma unroll
            for (int j = 0; j < KP; ++j) accbuf[((g-1)*TPG + kt)*KP + j] = (float)rank[j];
        }
    }
    __syncthreads();

    if (g == 0 && active) {
        #pragma unroll
        for (int j = 0; j < KP; ++j) {
            int r = rank[j];
            for (int gg = 1; gg < G; ++gg) r += (int)accbuf[((gg-1)*TPG + kt)*KP + j];
            if (r < KOUT) {
                const int k = kt + j*KUSE;
                const float2 p = cPos[k];
                const float4 c = cC[k];
                const float ww = w2s[k];
                float* dst = out_sel + (size_t)((b*LO + lo)*KOUT + r)*7;
                dst[0] = ww; dst[1] = p.x; dst[2] = p.y;
                dst[3] = c.x; dst[4] = c.y; dst[5] = c.z; dst[6] = c.w;
                const float det = c.x*c.w - c.y*c.z;
                selint[r] = sane(fabsf(ww) * TWO_PI_F * sqrtf(fmaxf(det, EPS_F)));
            }
        }
    }
    __syncthreads();
    if (tid == 0) {
        float s = 0.f;
        for (int i = 0; i < KOUT; ++i) s += selint[i];
        out_tot[b*LO + lo] = s;
    }

    // ---- FINAL tail: last-completing block runs batchnorm3+integrate+
    // log_softmax. Release: threadfence+atomicAdd; acquire: threadfence after.
    if constexpr (FINAL) {
        __shared__ unsigned int lastf;
        __shared__ float fscale[10];
        __shared__ float fint[BATCH*10];
        __syncthreads();
        if (tid == 0) {
            __threadfence();
            const unsigned int prev = atomicAdd(done, 1u);
            lastf = (prev == (unsigned int)(BATCH*LO - 1)) ? 1u : 0u;
        }
        __syncthreads();
        if (lastf) {
            __threadfence();   // acquire all blocks' out_sel/out_tot writes
            if (tid < 10) {
                float s = 0.f;
                for (int bb = 0; bb < BATCH; ++bb) s += out_tot[bb*10 + tid];
                fscale[tid] = 1.f / (s / (float)BATCH + EPS_F);
            }
            __syncthreads();
            if (tid < BATCH*10) {
                const int bb = tid / 10, l = tid % 10;
                const float* base = out_sel + (size_t)((bb*10 + l)*KOUT)*7;
                float s = 0.f;
                for (int kk = 0; kk < KOUT; ++kk) {
                    const float* c = base + kk*7;
                    const float det = c[3]*c[6] - c[4]*c[5];
                    s += c[0] * fscale[l] * TWO_PI_F * sqrtf(fmaxf(det, EPS_F));
                }
                fint[tid] = sane(s);
            }
            __syncthreads();
            if (tid < BATCH) {
                float m = -1e30f;
                for (int l = 0; l < 10; ++l) m = fmaxf(m, fint[tid*10 + l]);
                float ss = 0.f;
                for (int l = 0; l < 10; ++l) ss += __expf(fint[tid*10 + l] - m);
                const float lse = m + logf(ss);
                for (int l = 0; l < 10; ++l)
                    fout[tid*10 + l] = fint[tid*10 + l] - lse;
            }
        }
    }
}

extern "C" void kernel_launch(void* const* d_in, const int* in_sizes, int n_in,
                              void* d_out, int out_size, void* d_ws, size_t ws_size,
                              hipStream_t stream)
{
    const float* in_x = (const float*)d_in[0];
    const float* k1   = (const float*)d_in[1];
    const float* k2   = (const float*)d_in[2];
    const float* k3   = (const float*)d_in[3];
    const float* b1   = (const float*)d_in[4];
    const float* b2   = (const float*)d_in[5];
    const float* b3   = (const float*)d_in[6];
    float* out = (float*)d_out;   // reference output dtype is float32

    float* ws = (float*)d_ws;
    float* sel1 = ws;                  // 32*5*25*7  = 28000 floats
    float* tot1 = ws + 28000;          // 160
    float* sel2 = ws + 28160;          // 32*6*12*7  = 16128
    float* tot2 = ws + 44288;          // 192
    float* sel3 = ws + 44480;          // 32*10*5*7  = 11200
    float* tot3 = ws + 55680;          // 320
    unsigned int* cnt = (unsigned int*)(ws + 56064);  // L3 completion counter

    // Layer 1: 320 comps, keep 25. KP=5, TPG=64, G=16 -> 1024 threads.
    //          Also zeroes the L3 done-counter (stream order -> visible).
    layer_kernel<5, 1, 64, 5, 320, 25, 5, 64, 16, true, false>
        <<<BATCH*5, 1024, 0, stream>>>(
        in_x, nullptr, nullptr, k1, b1, sel1, tot1, cnt, nullptr, nullptr);
    // Layer 2: 625 comps, keep 12. KP=5, TPG=128, G=8 -> 1024 threads.
    layer_kernel<6, 5, 25, 5, 625, 12, 5, 128, 8, false, false>
        <<<BATCH*6, 1024, 0, stream>>>(
        nullptr, sel1, tot1, k2, b2, sel2, tot2, nullptr, nullptr, nullptr);
    // Layer 3 + fused final tail: 360 comps, keep 5. KP=6, TPG=64, G=12 -> 768.
    //          Last-completing block runs batchnorm3+integrate+log_softmax.
    layer_kernel<10, 6, 12, 5, 360, 5, 6, 64, 12, false, true>
        <<<BATCH*10, 768, 0, stream>>>(
        nullptr, sel2, tot2, k3, b3, sel3, tot3, nullptr, cnt, out);
}

// Round 16
// 146.445 us; speedup vs baseline: 1.0452x; 1.0246x over previous
//
#include <hip/hip_runtime.h>

#define TWO_PI_F 6.283185307179586f
#define EPS_F 1e-6f
#define LOG2E_F 1.4426950408889634f
#define BATCH 32

// Bare v_exp_f32 (2^x). libm exp2f wraps it with edge-case fixups (round-11
// measured: -11 us on layer 2 from dropping the wrapper).
#if __has_builtin(__builtin_amdgcn_exp2f)
#define EXP2F(x) __builtin_amdgcn_exp2f(x)
#else
#define EXP2F(x) exp2f(x)
#endif

typedef float v2f __attribute__((ext_vector_type(2)));

// Replace non-finite by 0 (bit test so fast-math can't fold it away).
__device__ __forceinline__ float sane(float x) {
    return ((__float_as_uint(x) & 0x7f800000u) == 0x7f800000u) ? 0.f : x;
}

// One fused layer: [prev batchnorm] -> gm_convolve -> eval_at_centers
// (polynomial form, k-slots paired for v_pk_fma_f32, 2-deep software-pipelined
// LDS broadcast) -> relu_fit (stable-rank top-KOUT) -> selected comps +
// per-(b,lo) abs-integral.   [round-13 measured optimum: 146.5 us total]
template<int LO, int LI, int ND, int NK, int NCOMP, int KOUT,
         int KP, int TPG, int G, bool FIRST>
__global__ __launch_bounds__(TPG*G) void layer_kernel(
    const float* __restrict__ in_x,            // FIRST: (B,1,64,7) f32
    const float* __restrict__ prev_sel,        // !FIRST: (B,LI,ND,7) f32
    const float* __restrict__ prev_tot,        // !FIRST: (B,LI) f32
    const float* __restrict__ kern,            // (LO,LI,NK,7) f32
    const float* __restrict__ bias,            // (LO,) f32
    float* __restrict__ out_sel,               // (B,LO,KOUT,7) f32
    float* __restrict__ out_tot)               // (B,LO) f32
{
    constexpr int KUSE   = NCOMP / KP;
    static_assert(KUSE * KP == NCOMP, "exact k tiling required");
    constexpr int CHUNK  = (NCOMP + G - 1) / G;
    constexpr int NCOMP4 = (NCOMP + 3) & ~3;
    constexpr int NQn    = NCOMP4 / 4;
    constexpr int CQ     = (NQn + G - 1) / G;
    constexpr int NPAIR  = KP / 2;
    constexpr int PPAD   = NPAIR > 0 ? NPAIR : 1;
    constexpr bool ODD   = (KP & 1) != 0;

    const int b   = blockIdx.x / LO;
    const int lo  = blockIdx.x % LO;
    const int tid = threadIdx.x;
    const int g   = tid / TPG;
    const int kt  = tid % TPG;
    const bool active = (kt < KUSE);

    // Staging arrays (dead after Phase A) union'd with accbuf (live Phase B+).
    struct StageT {
        float4 d_c[LI*ND];
        float4 k_c[LI*NK];
        float  d_w[LI*ND], d_px[LI*ND], d_py[LI*ND];
        float  k_w[LI*NK], k_px[LI*NK], k_py[LI*NK];
    };
    constexpr size_t ACCB = (size_t)(G > 1 ? (G-1)*TPG*KP : 1) * sizeof(float);
    constexpr size_t UB   = sizeof(StageT) > ACCB ? sizeof(StageT) : ACCB;
    __shared__ __align__(16) unsigned char u_smem[UB];
    StageT& st    = *reinterpret_cast<StageT*>(u_smem);
    float* accbuf = reinterpret_cast<float*>(u_smem);

    __shared__ float2 cPos[NCOMP];  // px, py
    __shared__ float4 nP[NCOMP];    // a, b, c, d (log2e-folded quadform poly)
    __shared__ float4 nQ[NCOMP];    // e, f, w, 0
    __shared__ float4 cC[NCOMP];    // C00,C01,C10,C11
    __shared__ float  w2s[NCOMP];
    __shared__ __align__(16) float a2s[NCOMP4];
    __shared__ float  scr[64];
    __shared__ float  selint[32];
    __shared__ float  dscale[LI];

    // ---- Phase pre: incoming batchnorm + stage data/kernel into LDS
    if constexpr (FIRST) {
        if (tid < ND) {
            const float* s = in_x + (size_t)(b*ND + tid)*7;
            const float w  = sane(s[0]);
            const float c0 = sane(s[3]), c1 = sane(s[4]), c2 = sane(s[5]), c3 = sane(s[6]);
            st.d_w[tid] = w; st.d_px[tid] = sane(s[1]); st.d_py[tid] = sane(s[2]);
            st.d_c[tid] = make_float4(c0, c1, c2, c3);
            const float det = c0*c3 - c1*c2;
            scr[tid] = sane(fabsf(w) * TWO_PI_F * sqrtf(fmaxf(det, EPS_F)));
        }
        __syncthreads();
        if (tid == 0) {
            float s = 0.f;
            for (int i = 0; i < ND; ++i) s += scr[i];
            dscale[0] = 1.f / (s + EPS_F);
        }
        __syncthreads();
        if (tid < ND) st.d_w[tid] = sane(st.d_w[tid] * dscale[0]);
    } else {
        if (tid < LI) {
            float s = 0.f;
            for (int bb = 0; bb < BATCH; ++bb) s += prev_tot[bb*LI + tid];
            dscale[tid] = 1.f / (s / (float)BATCH + EPS_F);
        }
        __syncthreads();
        if (tid < LI*ND) {
            const int li = tid / ND;
            const float* s = prev_sel + (size_t)(b*LI*ND + tid)*7;
            st.d_w[tid]  = sane(s[0] * dscale[li]);
            st.d_px[tid] = s[1]; st.d_py[tid] = s[2];
            st.d_c[tid]  = make_float4(s[3], s[4], s[5], s[6]);
        }
    }
    if (tid < LI*NK) {
        const float* s = kern + (size_t)(lo*LI*NK + tid)*7;
        st.k_w[tid]  = sane(s[0]);
        st.k_px[tid] = sane(s[1]); st.k_py[tid] = sane(s[2]);
        st.k_c[tid]  = make_float4(sane(s[3]), sane(s[4]), sane(s[5]), sane(s[6]));
    }
    __syncthreads();

    // ---- Phase A: gm_convolve -> poly coefficients in LDS.
    // Flattening matches reference reshape: (li, nd, nk), nk fastest.
    if (tid < NCOMP) {
        const int li = tid / (ND*NK);
        const int r  = tid % (ND*NK);
        const int nd = r / NK, nk = r % NK;
        const int di = li*ND + nd, ki = li*NK + nk;
        const float4 dc = st.d_c[di], kc = st.k_c[ki];
        const float c0 = dc.x + kc.x, c1 = dc.y + kc.y, c2 = dc.z + kc.z, c3 = dc.w + kc.w;
        const float dd = dc.x*dc.w - dc.y*dc.z;
        const float dk = kc.x*kc.w - kc.y*kc.z;
        const float ds = c0*c3 - c1*c2;
        const float w  = sane(st.d_w[di]*st.k_w[ki]*TWO_PI_F*sqrtf(fmaxf(dd*dk, 0.f) / fmaxf(ds, EPS_F)));
        const float px = sane(st.d_px[di] + st.k_px[ki]);
        const float py = sane(st.d_py[di] + st.k_py[ki]);
        const float inv = -0.5f * LOG2E_F / ds;
        const float a   = sane(c3*inv);
        const float bb  = sane(-(c1 + c2)*inv);
        const float cc  = sane(c0*inv);
        const float dd2 = sane(-(2.f*a*px + bb*py));
        const float ee  = sane(-(2.f*cc*py + bb*px));
        const float ff  = sane((a*px + bb*py)*px + cc*py*py);
        cPos[tid] = make_float2(px, py);
        nP[tid]   = make_float4(a, bb, cc, dd2);
        nQ[tid]   = make_float4(ee, ff, w, 0.f);
        cC[tid]   = make_float4(sane(c0), sane(c1), sane(c2), sane(c3));
    }
    __syncthreads();

    // ---- Phase B: eval_at_centers. k-slots paired (v_pk_fma_f32); per-n LDS
    // broadcast software-pipelined 2 deep: n+1's P/Q load issues before n's
    // exp chain, so the ds_read latency overlaps the FMA/exp work.
    v2f kxP[PPAD], kyP[PPAD], kx2P[PPAD], ky2P[PPAD], kxyP[PPAD], accP[PPAD];
    float kxS = 0.f, kyS = 0.f, kx2S = 0.f, ky2S = 0.f, kxyS = 0.f, accS = 0.f;
    #pragma unroll
    for (int p = 0; p < NPAIR; ++p) {
        float x0 = 0.f, y0 = 0.f, x1 = 0.f, y1 = 0.f;
        if (active) {
            const float2 p0 = cPos[kt + (2*p    )*KUSE];
            const float2 p1 = cPos[kt + (2*p + 1)*KUSE];
            x0 = p0.x; y0 = p0.y; x1 = p1.x; y1 = p1.y;
        }
        v2f kx; kx.x = x0; kx.y = x1;
        v2f ky; ky.x = y0; ky.y = y1;
        kxP[p] = kx; kyP[p] = ky;
        kx2P[p] = kx*kx; ky2P[p] = ky*ky; kxyP[p] = kx*ky;
        v2f z; z.x = 0.f; z.y = 0.f; accP[p] = z;
    }
    if constexpr (ODD) {
        if (active) { const float2 pz = cPos[kt + (KP-1)*KUSE]; kxS = pz.x; kyS = pz.y; }
        kx2S = kxS*kxS; ky2S = kyS*kyS; kxyS = kxS*kyS;
    }
    {
        const int n0 = g*CHUNK;
        const int n1 = (n0 + CHUNK < NCOMP) ? (n0 + CHUNK) : NCOMP;
        if (n0 < n1) {
            float4 P = nP[n0], Q = nQ[n0];
            #pragma unroll 2
            for (int n = n0; n < n1; ++n) {
                const int nn = (n + 1 < n1) ? n + 1 : n0;
                const float4 Pn = nP[nn];   // prefetch: issues before exp chain
                const float4 Qn = nQ[nn];
                v2f Pa; Pa.x = P.x; Pa.y = P.x;
                v2f Pb; Pb.x = P.y; Pb.y = P.y;
                v2f Pc; Pc.x = P.z; Pc.y = P.z;
                v2f Pd; Pd.x = P.w; Pd.y = P.w;
                v2f Qe; Qe.x = Q.x; Qe.y = Q.x;
                v2f Qf; Qf.x = Q.y; Qf.y = Q.y;
                v2f Qw; Qw.x = Q.z; Qw.y = Q.z;
                #pragma unroll
                for (int p = 0; p < NPAIR; ++p) {
                    const v2f md = __builtin_elementwise_fma(Pa, kx2P[p],
                                   __builtin_elementwise_fma(Pb, kxyP[p],
                                   __builtin_elementwise_fma(Pc, ky2P[p],
                                   __builtin_elementwise_fma(Pd, kxP[p],
                                   __builtin_elementwise_fma(Qe, kyP[p], Qf)))));
                    v2f ex; ex.x = EXP2F(md.x); ex.y = EXP2F(md.y);
                    accP[p] = __builtin_elementwise_fma(Qw, ex, accP[p]);
                }
                if constexpr (ODD) {
                    const float md = fmaf(P.x, kx2S,
                                     fmaf(P.y, kxyS,
                                     fmaf(P.z, ky2S,
                                     fmaf(P.w, kxS,
                                     fmaf(Q.x, kyS, Q.y)))));
                    accS = fmaf(Q.z, EXP2F(md), accS);
                }
                P = Pn; Q = Qn;
            }
        }
    }
    // Unpack pairs back to per-slot acc[]
    float acc[KP];
    #pragma unroll
    for (int p = 0; p < NPAIR; ++p) { acc[2*p] = accP[p].x; acc[2*p+1] = accP[p].y; }
    if constexpr (ODD) acc[KP-1] = accS;

    if (g > 0 && active) {
        #pragma unroll
        for (int j = 0; j < KP; ++j) accbuf[((g-1)*TPG + kt)*KP + j] = acc[j];
    }
    __syncthreads();

    const float bi = bias[lo];
    if (g == 0 && active) {
        #pragma unroll
        for (int j = 0; j < KP; ++j) {
            float s = acc[j];
            for (int gg = 1; gg < G; ++gg) s += accbuf[((gg-1)*TPG + kt)*KP + j];
            const float v  = s + bi;
            const float sc = fmaxf(v, 0.f) / (fabsf(v) + EPS_F);
            const int   k  = kt + j*KUSE;
            const float ww = sane(nQ[k].z * sc);
            w2s[k] = ww;
            a2s[k] = fabsf(ww);
        }
    }
    if constexpr (NCOMP4 > NCOMP) {
        if (tid >= NCOMP && tid < NCOMP4) a2s[tid] = -1.f;  // pad: never ranks
    }
    __syncthreads();

    // ---- Phase C: stable-descending rank (== jax.lax.top_k order), group-split
    int rank[KP];
    float myv[KP];
    #pragma unroll
    for (int j = 0; j < KP; ++j) rank[j] = 0;
    if (active) {
        #pragma unroll
        for (int j = 0; j < KP; ++j) myv[j] = a2s[kt + j*KUSE];
        const int q0 = g*CQ;
        const int q1 = (q0 + CQ < NQn) ? (q0 + CQ) : NQn;
        for (int q = q0; q < q1; ++q) {
            const float4 v4 = ((const float4*)a2s)[q];  // broadcast
            #pragma unroll
            for (int c = 0; c < 4; ++c) {
                const float vj = (c == 0) ? v4.x : (c == 1) ? v4.y : (c == 2) ? v4.z : v4.w;
                const int   jj = 4*q + c;
                #pragma unroll
                for (int j = 0; j < KP; ++j) {
                    const int myk = kt + j*KUSE;
                    rank[j] += (vj > myv[j] || (vj == myv[j] && jj < myk)) ? 1 : 0;
                }
            }
        }
        if (g > 0) {
            #pragma unroll
            for (int j = 0; j < KP; ++j) accbuf[((g-1)*TPG + kt)*KP + j] = (float)rank[j];
        }
    }
    __syncthreads();

    // ---- Phase D: g==0 finalizes ranks, writes selected comps + integrals
    if (g == 0 && active) {
        #pragma unroll
        for (int j = 0; j < KP; ++j) {
            int r = rank[j];
            for (int gg = 1; gg < G; ++gg) r += (int)accbuf[((gg-1)*TPG + kt)*KP + j];
            if (r < KOUT) {
                const int k = kt + j*KUSE;
                const float2 p = cPos[k];
                const float4 c = cC[k];
                const float ww = w2s[k];
                float* dst = out_sel + (size_t)((b*LO + lo)*KOUT + r)*7;
                dst[0] = ww; dst[1] = p.x; dst[2] = p.y;
                dst[3] = c.x; dst[4] = c.y; dst[5] = c.z; dst[6] = c.w;
                const float det = c.x*c.w - c.y*c.z;
                selint[r] = sane(fabsf(ww) * TWO_PI_F * sqrtf(fmaxf(det, EPS_F)));
            }
        }
    }
    __syncthreads();
    if (tid == 0) {
        float s = 0.f;
        for (int i = 0; i < KOUT; ++i) s += selint[i];
        out_tot[b*LO + lo] = s;
    }
}

// Final: batchnorm3 scale (mean over batch) -> integrate -> log_softmax -> f32
__global__ __launch_bounds__(64) void final_kernel(
    const float* __restrict__ sel3,   // (B,10,5,7)
    const float* __restrict__ tot3,   // (B,10)
    float* __restrict__ out)          // (B,10) f32
{
    const int b = blockIdx.x;
    const int tid = threadIdx.x;
    __shared__ float scale3[10], integ[10], red2[2];
    if (tid < 10) {
        float s = 0.f;
        for (int bb = 0; bb < BATCH; ++bb) s += tot3[bb*10 + tid];
        scale3[tid] = 1.f / (s / (float)BATCH + EPS_F);
    }
    __syncthreads();
    if (tid < 10) {
        float s = 0.f;
        const float* base = sel3 + (size_t)((b*10 + tid)*5)*7;
        for (int kk = 0; kk < 5; ++kk) {
            const float* c = base + kk*7;
            const float det = c[3]*c[6] - c[4]*c[5];
            s += c[0] * scale3[tid] * TWO_PI_F * sqrtf(fmaxf(det, EPS_F));
        }
        integ[tid] = sane(s);
    }
    __syncthreads();
    if (tid == 0) {
        float m = -1e30f;
        for (int l = 0; l < 10; ++l) m = fmaxf(m, integ[l]);
        float ss = 0.f;
        for (int l = 0; l < 10; ++l) ss += __expf(integ[l] - m);
        red2[0] = m; red2[1] = logf(ss);
    }
    __syncthreads();
    if (tid < 10) out[b*10 + tid] = integ[tid] - red2[0] - red2[1];
}

extern "C" void kernel_launch(void* const* d_in, const int* in_sizes, int n_in,
                              void* d_out, int out_size, void* d_ws, size_t ws_size,
                              hipStream_t stream)
{
    const float* in_x = (const float*)d_in[0];
    const float* k1   = (const float*)d_in[1];
    const float* k2   = (const float*)d_in[2];
    const float* k3   = (const float*)d_in[3];
    const float* b1   = (const float*)d_in[4];
    const float* b2   = (const float*)d_in[5];
    const float* b3   = (const float*)d_in[6];
    float* out = (float*)d_out;   // reference output dtype is float32

    float* ws = (float*)d_ws;
    float* sel1 = ws;                  // 32*5*25*7  = 28000 floats
    float* tot1 = ws + 28000;          // 160
    float* sel2 = ws + 28160;          // 32*6*12*7  = 16128
    float* tot2 = ws + 44288;          // 192
    float* sel3 = ws + 44480;          // 32*10*5*7  = 11200
    float* tot3 = ws + 55680;          // 320  (total ~224 KB)

    // Layer 1: 320 comps, keep 25.  KP=5 (64*5=320), TPG=64, G=16 -> NT=1024.
    layer_kernel<5, 1, 64, 5, 320, 25, 5, 64, 16, true><<<BATCH*5, 1024, 0, stream>>>(
        in_x, nullptr, nullptr, k1, b1, sel1, tot1);
    // Layer 2: 625 comps, keep 12.  KP=5 (125*5=625), TPG=128, G=8 -> NT=1024.
    layer_kernel<6, 5, 25, 5, 625, 12, 5, 128, 8, false><<<BATCH*6, 1024, 0, stream>>>(
        nullptr, sel1, tot1, k2, b2, sel2, tot2);
    // Layer 3: 360 comps, keep 5.   KP=6 (60*6=360), TPG=64, G=12 -> NT=768.
    layer_kernel<10, 6, 12, 5, 360, 5, 6, 64, 12, false><<<BATCH*10, 768, 0, stream>>>(
        nullptr, sel2, tot2, k3, b3, sel3, tot3);
    // Final: batchnorm + integrate + log_softmax.
    final_kernel<<<BATCH, 64, 0, stream>>>(sel3, tot3, out);
}